// Round 5
// baseline (229.471 us; speedup 1.0000x reference)
//
#include <hip/hip_runtime.h>

// DfOp v5: (A) PERSISTENT grid-stride copy spec->out + (B) filtered-band FIR.
// v4 post-mortem: branch-free one-shot copy (4 f4 in flight) was NEUTRAL —
// still ~55 us / 2.5 TB/s. The harness fill (persistent loop, 9% occupancy)
// hits 6.6 TB/s; m13's 6.29 TB/s copy is also grid-stride. The limiting
// regime is one-shot wave churn (22k short waves paying ramp/drain for one
// batch), not per-wave ILP. v5: 1024 persistent blocks, 8 float4 per thread
// per iteration, loads batched before stores. B unchanged for clean A/B.

#define BN    8
#define TN    3000
#define FN    481
#define NDF   96
#define NORD  5
#define ROWF  (FN * 2)       // floats per (b,t) row = 962
#define THALF (TN / 2)       // 1500 t-pairs

#define N4     (BN * TN * FN * 2 / 4)   // 5,772,000 float4 elements
#define CPB    2048                     // float4 per chunk (256 thr x 8)
#define NCHUNK (N4 / CPB)               // 2818 full chunks (tail = 736)
#define GRIDA  1024                     // persistent blocks

typedef float f2 __attribute__((ext_vector_type(2)));

// ---------------- Kernel A: persistent grid-stride copy ----------------
__global__ __launch_bounds__(256) void copy_kernel(const float4* __restrict__ in,
                                                   float4* __restrict__ out) {
    const int tid = threadIdx.x;
    for (int c = blockIdx.x; c < NCHUNK; c += GRIDA) {
        const int base = c * CPB + tid;
        // 8 loads in flight, then 8 stores (no guards in steady state)
        const float4 x0 = in[base];
        const float4 x1 = in[base + 256];
        const float4 x2 = in[base + 512];
        const float4 x3 = in[base + 768];
        const float4 x4 = in[base + 1024];
        const float4 x5 = in[base + 1280];
        const float4 x6 = in[base + 1536];
        const float4 x7 = in[base + 1792];
        out[base]        = x0;
        out[base + 256]  = x1;
        out[base + 512]  = x2;
        out[base + 768]  = x3;
        out[base + 1024] = x4;
        out[base + 1280] = x5;
        out[base + 1536] = x6;
        out[base + 1792] = x7;
    }
    // tail: float4s [NCHUNK*CPB, N4) — 736 elements, block 0 only
    if (blockIdx.x == 0) {
        for (int idx = NCHUNK * CPB + tid; idx < N4; idx += 256) out[idx] = in[idx];
    }
}

// ---------------- Kernel B: filtered band (bins 0..95) ----------------
__global__ __launch_bounds__(256) void df_filt_kernel(const float* __restrict__ spec,
                                                      const float* __restrict__ coef,
                                                      float* __restrict__ out) {
    const int i = blockIdx.x * blockDim.x + threadIdx.x;
    const int nFiltP = BN * THALF * NDF;     // 1,152,000 pair-threads
    if (i >= nFiltP) return;

    const int f   = i % NDF;
    const int bth = i / NDF;
    const int th  = bth % THALF;
    const int b   = bth / THALF;
    const int t0  = th * 2;
    const int bt0   = b * TN + t0;
    const int base0 = bt0 * ROWF + f * 2;        // float idx of (b,t0,f,0)

    // ---- issue all loads before compute ----
    const f2* cp = (const f2*)(coef + (bt0 * NDF + f) * (2 * NORD));
    const f2* cq = cp + NDF * NORD;              // next t row's coef
    const f2 c0a = cp[0], c0b = cp[1], c0c = cp[2], c0d = cp[3], c0e = cp[4];
    const f2 c1a = cq[0], c1b = cq[1], c1c = cq[2], c1d = cq[3], c1e = cq[4];

    const float* sp = spec + base0;
    f2 x0, x1, x2, x3, x4, x5;                   // rows t0-4 .. t0+1 at bin f
    if (t0 >= NORD - 1) {                        // fast path: 1498 of 1500 pairs
        x0 = *(const f2*)(sp - 4 * ROWF);
        x1 = *(const f2*)(sp - 3 * ROWF);
        x2 = *(const f2*)(sp - 2 * ROWF);
        x3 = *(const f2*)(sp - 1 * ROWF);
        x4 = *(const f2*)(sp);
        x5 = *(const f2*)(sp + 1 * ROWF);
    } else {                                     // t0 in {0,2}: zero-pad
        const f2 z = {0.f, 0.f};
        x0 = (t0 >= 4) ? *(const f2*)(sp - 4 * ROWF) : z;
        x1 = (t0 >= 3) ? *(const f2*)(sp - 3 * ROWF) : z;
        x2 = (t0 >= 2) ? *(const f2*)(sp - 2 * ROWF) : z;
        x3 = (t0 >= 1) ? *(const f2*)(sp - 1 * ROWF) : z;
        x4 = *(const f2*)(sp);
        x5 = *(const f2*)(sp + 1 * ROWF);
    }

    float fr0, fi0, fr1, fi1;
    {   // t0 output: taps x0..x4, coef c0 (cr[k]=coef[k], ci[k]=coef[5+k])
        const float cr0 = c0a.x, cr1 = c0a.y, cr2 = c0b.x, cr3 = c0b.y, cr4 = c0c.x;
        const float ci0 = c0c.y, ci1 = c0d.x, ci2 = c0d.y, ci3 = c0e.x, ci4 = c0e.y;
        fr0 = x0.x*cr0 - x0.y*ci0; fi0 = x0.x*ci0 + x0.y*cr0;
        fr0 += x1.x*cr1 - x1.y*ci1; fi0 += x1.x*ci1 + x1.y*cr1;
        fr0 += x2.x*cr2 - x2.y*ci2; fi0 += x2.x*ci2 + x2.y*cr2;
        fr0 += x3.x*cr3 - x3.y*ci3; fi0 += x3.x*ci3 + x3.y*cr3;
        fr0 += x4.x*cr4 - x4.y*ci4; fi0 += x4.x*ci4 + x4.y*cr4;
    }
    {   // t0+1 output: taps x1..x5, coef c1
        const float cr0 = c1a.x, cr1 = c1a.y, cr2 = c1b.x, cr3 = c1b.y, cr4 = c1c.x;
        const float ci0 = c1c.y, ci1 = c1d.x, ci2 = c1d.y, ci3 = c1e.x, ci4 = c1e.y;
        fr1 = x1.x*cr0 - x1.y*ci0; fi1 = x1.x*ci0 + x1.y*cr0;
        fr1 += x2.x*cr1 - x2.y*ci1; fi1 += x2.x*ci1 + x2.y*cr1;
        fr1 += x3.x*cr2 - x3.y*ci2; fi1 += x3.x*ci2 + x3.y*cr2;
        fr1 += x4.x*cr3 - x4.y*ci3; fi1 += x4.x*ci3 + x4.y*cr3;
        fr1 += x5.x*cr4 - x5.y*ci4; fi1 += x5.x*ci4 + x5.y*cr4;
    }

    *(f2*)(out + base0)        = (f2){fr0, fi0};
    *(f2*)(out + base0 + ROWF) = (f2){fr1, fi1};
}

extern "C" void kernel_launch(void* const* d_in, const int* in_sizes, int n_in,
                              void* d_out, int out_size, void* d_ws, size_t ws_size,
                              hipStream_t stream) {
    const float* spec = (const float*)d_in[0];
    const float* coef = (const float*)d_in[1];
    float* out = (float*)d_out;

    // A: persistent flat copy of the whole spec tensor
    copy_kernel<<<GRIDA, 256, 0, stream>>>((const float4*)spec, (float4*)out);

    // B: overwrite filtered band (stream-ordered after A)
    const int nFiltP = BN * THALF * NDF;        // 1,152,000
    const int gridB = (nFiltP + 255) / 256;     // 4500
    df_filt_kernel<<<gridB, 256, 0, stream>>>(spec, coef, out);
}

// Round 6
// 227.142 us; speedup vs baseline: 1.0103x; 1.0103x over previous
//
#include <hip/hip_runtime.h>

// DfOp v6: single fused kernel, block-role split, minimal traffic.
// v5 post-mortem: copy BW is shape-insensitive (2.5 TB/s for 3 structures);
// filt's read-rate (3.35 TB/s) is exactly 2x copy's (1.69) => loads/stores
// share VMEM queue slots; 1:1 copies starve reads. Also L3 is flushed by
// 2x360MB poison fills each iteration, so reads are cold-HBM.
// Fix: (1) cut bytes to compulsory minimum — passthrough blocks copy ONLY
// bins [96,481) (per row: 192 float4 + 1 float2, parity-dependent align),
// filt blocks write bins [0,96) — disjoint, no ordering needed;
// (2) interleave roles (blockIdx%5: 2 pass + 3 filt) to blend the R:W mix.
// Traffic: R 184.6 MB + W 92.4 MB = 277 MB (v5: 314 MB).

#define BN    8
#define TN    3000
#define FN    481
#define NDF   96
#define NORD  5
#define ROWF  (FN * 2)        // 962 floats per (b,t) row
#define THALF (TN / 2)        // 1500 t-pairs
#define NROWS (BN * TN)       // 24000 rows
#define RPB   8               // rows per passthrough block
#define NPB   (NROWS / RPB)   // 3000 passthrough blocks
#define NFB   ((BN * THALF * NDF) / 256)  // 4500 filt blocks (exact)

typedef float f2 __attribute__((ext_vector_type(2)));

__global__ __launch_bounds__(256) void df_kernel(const float* __restrict__ spec,
                                                 const float* __restrict__ coef,
                                                 float* __restrict__ out) {
    const int tid = threadIdx.x;
    const int m   = blockIdx.x % 5;

    if (m < 2) {
        // ---- passthrough role: copy bins [96,481) of 8 rows ----
        // Row r floats [962r+192, 962r+962) = 770 floats.
        // r even: 192 f4 at 962r+192 (16B aligned) + f2 at 962r+960.
        // r odd : f2 at 962r+192 (8B aligned) + 192 f4 at 962r+194.
        const int p  = (blockIdx.x / 5) * 2 + m;   // [0, 3000)
        const int r0 = p * RPB;
        const float4* in4  = (const float4*)spec;
        float4*       out4 = (float4*)out;

        int a0, a1, a2, a3, a4, a5;
        #define PASS_ADDR(j, dst)                                         \
            {                                                             \
                const int L  = tid + (j) * 256;                           \
                const int rl = L / 192;                                   \
                const int k  = L - rl * 192;                              \
                const int r  = r0 + rl;                                   \
                const int q0 = (ROWF * r + ((r & 1) ? 194 : 192)) >> 2;   \
                dst = q0 + k;                                             \
            }
        PASS_ADDR(0, a0) PASS_ADDR(1, a1) PASS_ADDR(2, a2)
        PASS_ADDR(3, a3) PASS_ADDR(4, a4) PASS_ADDR(5, a5)
        #undef PASS_ADDR

        // all loads issued before any store (slot/ILP friendly)
        const float4 x0 = in4[a0];
        const float4 x1 = in4[a1];
        const float4 x2 = in4[a2];
        const float4 x3 = in4[a3];
        const float4 x4 = in4[a4];
        const float4 x5 = in4[a5];

        f2 e; int eidx = 0;
        if (tid < RPB) {                           // one leftover f2 per row
            const int r = r0 + tid;
            eidx = ROWF * r + ((r & 1) ? 192 : 960);
            e = *(const f2*)(spec + eidx);
        }

        out4[a0] = x0; out4[a1] = x1; out4[a2] = x2;
        out4[a3] = x3; out4[a4] = x4; out4[a5] = x5;
        if (tid < RPB) *(f2*)(out + eidx) = e;
    } else {
        // ---- filt role: bins [0,96), pair of consecutive t per thread ----
        const int q = (blockIdx.x / 5) * 3 + (m - 2);  // [0, 4500)
        const int i = q * 256 + tid;                   // < 1,152,000 exactly

        const int f   = i % NDF;
        const int bth = i / NDF;
        const int th  = bth % THALF;
        const int b   = bth / THALF;
        const int t0  = th * 2;
        const int bt0   = b * TN + t0;
        const int base0 = bt0 * ROWF + f * 2;          // (b,t0,f,0)

        const f2* cp = (const f2*)(coef + (bt0 * NDF + f) * (2 * NORD));
        const f2* cq = cp + NDF * NORD;                // next t row's coef
        const f2 c0a = cp[0], c0b = cp[1], c0c = cp[2], c0d = cp[3], c0e = cp[4];
        const f2 c1a = cq[0], c1b = cq[1], c1c = cq[2], c1d = cq[3], c1e = cq[4];

        const float* sp = spec + base0;
        f2 x0, x1, x2, x3, x4, x5;                     // rows t0-4 .. t0+1
        if (t0 >= NORD - 1) {                          // fast path
            x0 = *(const f2*)(sp - 4 * ROWF);
            x1 = *(const f2*)(sp - 3 * ROWF);
            x2 = *(const f2*)(sp - 2 * ROWF);
            x3 = *(const f2*)(sp - 1 * ROWF);
            x4 = *(const f2*)(sp);
            x5 = *(const f2*)(sp + 1 * ROWF);
        } else {                                       // t0 in {0,2}
            const f2 z = {0.f, 0.f};
            x0 = (t0 >= 4) ? *(const f2*)(sp - 4 * ROWF) : z;
            x1 = (t0 >= 3) ? *(const f2*)(sp - 3 * ROWF) : z;
            x2 = (t0 >= 2) ? *(const f2*)(sp - 2 * ROWF) : z;
            x3 = (t0 >= 1) ? *(const f2*)(sp - 1 * ROWF) : z;
            x4 = *(const f2*)(sp);
            x5 = *(const f2*)(sp + 1 * ROWF);
        }

        float fr0, fi0, fr1, fi1;
        {   // t0: taps x0..x4, coef c0 (cr[k]=coef[k], ci[k]=coef[5+k])
            const float cr0 = c0a.x, cr1 = c0a.y, cr2 = c0b.x, cr3 = c0b.y, cr4 = c0c.x;
            const float ci0 = c0c.y, ci1 = c0d.x, ci2 = c0d.y, ci3 = c0e.x, ci4 = c0e.y;
            fr0 = x0.x*cr0 - x0.y*ci0; fi0 = x0.x*ci0 + x0.y*cr0;
            fr0 += x1.x*cr1 - x1.y*ci1; fi0 += x1.x*ci1 + x1.y*cr1;
            fr0 += x2.x*cr2 - x2.y*ci2; fi0 += x2.x*ci2 + x2.y*cr2;
            fr0 += x3.x*cr3 - x3.y*ci3; fi0 += x3.x*ci3 + x3.y*cr3;
            fr0 += x4.x*cr4 - x4.y*ci4; fi0 += x4.x*ci4 + x4.y*cr4;
        }
        {   // t0+1: taps x1..x5, coef c1
            const float cr0 = c1a.x, cr1 = c1a.y, cr2 = c1b.x, cr3 = c1b.y, cr4 = c1c.x;
            const float ci0 = c1c.y, ci1 = c1d.x, ci2 = c1d.y, ci3 = c1e.x, ci4 = c1e.y;
            fr1 = x1.x*cr0 - x1.y*ci0; fi1 = x1.x*ci0 + x1.y*cr0;
            fr1 += x2.x*cr1 - x2.y*ci1; fi1 += x2.x*ci1 + x2.y*cr1;
            fr1 += x3.x*cr2 - x3.y*ci2; fi1 += x3.x*ci2 + x3.y*cr2;
            fr1 += x4.x*cr3 - x4.y*ci3; fi1 += x4.x*ci3 + x4.y*cr3;
            fr1 += x5.x*cr4 - x5.y*ci4; fi1 += x5.x*ci4 + x5.y*cr4;
        }

        *(f2*)(out + base0)        = (f2){fr0, fi0};
        *(f2*)(out + base0 + ROWF) = (f2){fr1, fi1};
    }
}

extern "C" void kernel_launch(void* const* d_in, const int* in_sizes, int n_in,
                              void* d_out, int out_size, void* d_ws, size_t ws_size,
                              hipStream_t stream) {
    const float* spec = (const float*)d_in[0];
    const float* coef = (const float*)d_in[1];
    float* out = (float*)d_out;

    const int grid = NPB + NFB;        // 3000 + 4500 = 7500 (%5 == 0)
    df_kernel<<<grid, 256, 0, stream>>>(spec, coef, out);
}